// Round 2
// baseline (936.465 us; speedup 1.0000x reference)
//
#include <hip/hip_runtime.h>
#include <math.h>

#define HID 256
#define PTS 16                 // points per block
#define NSTR 5                 // value, g0, g1, g2, laplacian-sum T
#define ROWS (NSTR*PTS)        // 80
#define PITCH 272              // halves; 544B row stride; A-frag reads at bank floor

typedef _Float16 half4v __attribute__((ext_vector_type(4)));
typedef _Float16 half8  __attribute__((ext_vector_type(8)));
typedef float   floatx4 __attribute__((ext_vector_type(4)));

constexpr double PI_D = 3.14159265358979323846;
constexpr float K2F = (float)((343.0/(2.0*PI_D*1000.0))*(343.0/(2.0*PI_D*1000.0)));

__device__ __forceinline__ float tanh_fast(float z) {
  float e = __expf(2.0f*z);
  return 1.0f - 2.0f * __builtin_amdgcn_rcpf(e + 1.0f);
}

// Pack W2,W3 (fp32 row-major [k][n]) into fp16 B-fragment order for
// v_mfma_f32_16x16x32_f16, with a COLUMN PERMUTATION chosen so that in the
// D-layout, one lane's 4 tiles hold 4 CONSECUTIVE logical columns:
//   tile nt (= w*4+c), slot m  ->  logical col n = w*64 + m*4 + c
__global__ void pack_kernel(const float* __restrict__ W2, const float* __restrict__ W3,
                            _Float16* __restrict__ out, float* __restrict__ d_out) {
  int t = blockIdx.x * blockDim.x + threadIdx.x;   // 0..16383
  if (t == 0) d_out[0] = 0.0f;                     // zero the loss accumulator
  int l    = t >> 13;
  int rem  = t & 8191;
  int kc   = rem >> 10;
  int nt   = (rem >> 6) & 15;
  int lane = rem & 63;
  const float* W = l ? W3 : W2;
  int k0 = kc*32 + ((lane >> 4) << 3);
  int n  = (nt >> 2)*64 + (lane & 15)*4 + (nt & 3);   // permuted column
  _Float16* o = out + (size_t)t * 8;
  #pragma unroll
  for (int j = 0; j < 8; ++j)
    o[j] = (_Float16)W[(size_t)(k0 + j)*HID + n];
}

__global__ __launch_bounds__(256, 3) void helm_kernel(
    const float* __restrict__ inputs,
    const float* __restrict__ W1, const float* __restrict__ b1,
    const float* __restrict__ b2, const float* __restrict__ b3,
    const float* __restrict__ W4, const float* __restrict__ b4,
    const _Float16* __restrict__ Wpack,   // [2][65536] fp16, B-frag packed+permuted
    float* __restrict__ out, int N)
{
  __shared__ __align__(16) _Float16 X[ROWS][PITCH];

  const int tid  = threadIdx.x;
  const int lane = tid & 63;
  const int wave = tid >> 6;
  const int m    = lane & 15;   // A-row / D-col-slot within tile
  const int q    = lane >> 4;   // quad

  const int pbase = blockIdx.x * PTS;

  // ---------------- Layer 1: 3 -> 256 (VALU), vectorized staging ----------------
  {
    const int p  = tid >> 4;          // one point per 16 threads
    const int c0 = (tid & 15) * 16;   // 16 columns per thread
    const float x0 = inputs[(size_t)(pbase + p)*3 + 0];
    const float x1 = inputs[(size_t)(pbase + p)*3 + 1];
    const float x2 = inputs[(size_t)(pbase + p)*3 + 2];
    #pragma unroll
    for (int ch = 0; ch < 2; ++ch) {
      _Float16 o[NSTR][8];
      #pragma unroll
      for (int jj = 0; jj < 2; ++jj) {
        const int n = c0 + ch*8 + jj*4;
        floatx4 w0 = *(const floatx4*)&W1[0*HID + n];
        floatx4 w1 = *(const floatx4*)&W1[1*HID + n];
        floatx4 w2 = *(const floatx4*)&W1[2*HID + n];
        floatx4 bn = *(const floatx4*)&b1[n];
        #pragma unroll
        for (int e = 0; e < 4; ++e) {
          float z  = fmaf(x2, w2[e], fmaf(x1, w1[e], fmaf(x0, w0[e], bn[e])));
          float a  = tanh_fast(z);
          float dd = 1.0f - a*a;
          float wsq = w0[e]*w0[e] + w1[e]*w1[e] + w2[e]*w2[e];
          o[0][jj*4+e] = (_Float16)a;
          o[1][jj*4+e] = (_Float16)(dd*w0[e]);
          o[2][jj*4+e] = (_Float16)(dd*w1[e]);
          o[3][jj*4+e] = (_Float16)(dd*w2[e]);
          o[4][jj*4+e] = (_Float16)(-2.0f*a*dd*wsq);
        }
      }
      #pragma unroll
      for (int s = 0; s < NSTR; ++s)
        *(half8*)(&X[s*PTS + p][c0 + ch*8]) = *(half8*)(o[s]);
    }
  }
  __syncthreads();

  // ---------------- Layers 2,3: 256 -> 256 (MFMA) ----------------
  const int colbase = wave*64 + m*4;   // this lane's 4 consecutive logical cols
  for (int L = 0; L < 2; ++L) {
    const _Float16* Wp = Wpack + (size_t)L * 65536;
    const float* bb = L ? b3 : b2;

    floatx4 acc[NSTR][4];
    #pragma unroll
    for (int s = 0; s < NSTR; ++s)
      #pragma unroll
      for (int c = 0; c < 4; ++c)
        acc[s][c] = (floatx4){0.0f, 0.0f, 0.0f, 0.0f};

    // B-frag base for this wave's 4 tiles (c stride 512 halves, kc stride 8192)
    const _Float16* wb = Wp + (((size_t)(wave*4)*64 + lane) << 3);

    half8 bcur[4], bnxt[4];
    #pragma unroll
    for (int c = 0; c < 4; ++c)
      bcur[c] = *(const half8*)(wb + c*512);

    for (int kc = 0; kc < 8; ++kc) {
      const int kn = (kc + 1) & 7;               // branchless prefetch (last wraps, harmless)
      #pragma unroll
      for (int c = 0; c < 4; ++c)
        bnxt[c] = *(const half8*)(wb + (size_t)kn*8192 + c*512);
      half8 afrag[NSTR];
      #pragma unroll
      for (int s = 0; s < NSTR; ++s)
        afrag[s] = *(const half8*)(&X[s*PTS + m][kc*32 + q*8]);
      #pragma unroll
      for (int s = 0; s < NSTR; ++s)
        #pragma unroll
        for (int c = 0; c < 4; ++c)
          acc[s][c] = __builtin_amdgcn_mfma_f32_16x16x32_f16(afrag[s], bcur[c], acc[s][c], 0, 0, 0);
      #pragma unroll
      for (int c = 0; c < 4; ++c)
        bcur[c] = bnxt[c];
    }
    __syncthreads();   // everyone done reading X -> safe to overwrite in place

    floatx4 bv = *(const floatx4*)&bb[colbase];
    #pragma unroll
    for (int r = 0; r < 4; ++r) {
      const int p = q*4 + r;          // D-layout: row = quad*4 + reg
      _Float16 o[NSTR][4];
      #pragma unroll
      for (int c = 0; c < 4; ++c) {   // c-th tile = logical col colbase+c
        float z  = acc[0][c][r] + bv[c];
        float a  = tanh_fast(z);
        float dd = 1.0f - a*a;
        float zp0 = acc[1][c][r], zp1 = acc[2][c][r], zp2 = acc[3][c][r];
        float zpp = acc[4][c][r];
        float s2  = zp0*zp0 + zp1*zp1 + zp2*zp2;
        o[0][c] = (_Float16)a;
        o[1][c] = (_Float16)(dd*zp0);
        o[2][c] = (_Float16)(dd*zp1);
        o[3][c] = (_Float16)(dd*zp2);
        o[4][c] = (_Float16)(fmaf(dd, zpp, -2.0f*a*dd*s2));
      }
      #pragma unroll
      for (int s = 0; s < NSTR; ++s)
        *(half4v*)(&X[s*PTS + p][colbase]) = *(half4v*)(o[s]);  // 8B, conflict-free
    }
    __syncthreads();
  }

  // ---------------- Layer 4: 256 -> 1, residual, reduction ----------------
  float resacc = 0.0f;
  #pragma unroll
  for (int pp = 0; pp < 4; ++pp) {
    const int p = wave*4 + pp;
    half4v  xu = *(const half4v*)&X[0*PTS + p][lane*4];
    half4v  xt = *(const half4v*)&X[4*PTS + p][lane*4];
    floatx4 w4 = *(const floatx4*)&W4[lane*4];
    float su = 0.0f, st = 0.0f;
    #pragma unroll
    for (int e = 0; e < 4; ++e) {
      su = fmaf((float)xu[e], w4[e], su);
      st = fmaf((float)xt[e], w4[e], st);
    }
    #pragma unroll
    for (int off = 32; off; off >>= 1) {
      su += __shfl_down(su, off);
      st += __shfl_down(st, off);
    }
    if (lane == 0) {
      float u   = su + b4[0];
      float res = st + K2F * u;
      resacc = fmaf(res, res, resacc);
    }
  }
  if (lane == 0) atomicAdd(out, resacc * (1.0f / (float)N));
}

extern "C" void kernel_launch(void* const* d_in, const int* in_sizes, int n_in,
                              void* d_out, int out_size, void* d_ws, size_t ws_size,
                              hipStream_t stream) {
  const float* inputs = (const float*)d_in[0];
  const float* W1 = (const float*)d_in[1];
  const float* b1 = (const float*)d_in[2];
  const float* W2 = (const float*)d_in[3];
  const float* b2 = (const float*)d_in[4];
  const float* W3 = (const float*)d_in[5];
  const float* b3 = (const float*)d_in[6];
  const float* W4 = (const float*)d_in[7];
  const float* b4 = (const float*)d_in[8];
  float* out = (float*)d_out;
  _Float16* wp = (_Float16*)d_ws;   // needs 2*65536*2 = 256 KiB of workspace

  int N = in_sizes[0] / 3;          // 262144

  pack_kernel<<<64, 256, 0, stream>>>(W2, W3, wp, out);
  helm_kernel<<<N / PTS, 256, 0, stream>>>(inputs, W1, b1, b2, b3, W4, b4, wp, out, N);
}

// Round 3
// 467.687 us; speedup vs baseline: 2.0023x; 2.0023x over previous
//
#include <hip/hip_runtime.h>
#include <math.h>

#define HID 256
#define PTS 16                 // points per block
#define NSTR 5                 // value, g0, g1, g2, laplacian-sum T
#define ROWS (NSTR*PTS)        // 80
#define PITCH 272              // halves; 544B row stride; A-frag reads at bank floor

typedef _Float16 half4v __attribute__((ext_vector_type(4)));
typedef _Float16 half8  __attribute__((ext_vector_type(8)));
typedef float   floatx4 __attribute__((ext_vector_type(4)));

constexpr double PI_D = 3.14159265358979323846;
constexpr float K2F = (float)((343.0/(2.0*PI_D*1000.0))*(343.0/(2.0*PI_D*1000.0)));

__device__ __forceinline__ float tanh_fast(float z) {
  float e = __expf(2.0f*z);
  return 1.0f - 2.0f * __builtin_amdgcn_rcpf(e + 1.0f);
}

// Pack W2,W3 (fp32 row-major [k][n]) into fp16 B-fragment order for
// v_mfma_f32_16x16x32_f16, with a COLUMN PERMUTATION chosen so that in the
// D-layout, one lane's 4 tiles hold 4 CONSECUTIVE logical columns:
//   tile nt (= w*4+c), slot m  ->  logical col n = w*64 + m*4 + c
__global__ void pack_kernel(const float* __restrict__ W2, const float* __restrict__ W3,
                            _Float16* __restrict__ out) {
  int t = blockIdx.x * blockDim.x + threadIdx.x;   // 0..16383
  int l    = t >> 13;
  int rem  = t & 8191;
  int kc   = rem >> 10;
  int nt   = (rem >> 6) & 15;
  int lane = rem & 63;
  const float* W = l ? W3 : W2;
  int k0 = kc*32 + ((lane >> 4) << 3);
  int n  = (nt >> 2)*64 + (lane & 15)*4 + (nt & 3);   // permuted column
  _Float16* o = out + (size_t)t * 8;
  #pragma unroll
  for (int j = 0; j < 8; ++j)
    o[j] = (_Float16)W[(size_t)(k0 + j)*HID + n];
}

__global__ __launch_bounds__(256, 3) void helm_kernel(
    const float* __restrict__ inputs,
    const float* __restrict__ W1, const float* __restrict__ b1,
    const float* __restrict__ b2, const float* __restrict__ b3,
    const float* __restrict__ W4, const float* __restrict__ b4,
    const _Float16* __restrict__ Wpack,   // [2][65536] fp16, B-frag packed+permuted
    float* __restrict__ part)             // [gridDim.x] block partial sums
{
  __shared__ __align__(16) _Float16 X[ROWS][PITCH];
  __shared__ float sred[4];

  const int tid  = threadIdx.x;
  const int lane = tid & 63;
  const int wave = tid >> 6;
  const int m    = lane & 15;   // A-row / D-col-slot within tile
  const int q    = lane >> 4;   // quad

  const int pbase = blockIdx.x * PTS;

  // ---------------- Layer 1: 3 -> 256 (VALU), vectorized staging ----------------
  {
    const int p  = tid >> 4;          // one point per 16 threads
    const int c0 = (tid & 15) * 16;   // 16 columns per thread
    const float x0 = inputs[(size_t)(pbase + p)*3 + 0];
    const float x1 = inputs[(size_t)(pbase + p)*3 + 1];
    const float x2 = inputs[(size_t)(pbase + p)*3 + 2];
    #pragma unroll
    for (int ch = 0; ch < 2; ++ch) {
      _Float16 o[NSTR][8];
      #pragma unroll
      for (int jj = 0; jj < 2; ++jj) {
        const int n = c0 + ch*8 + jj*4;
        floatx4 w0 = *(const floatx4*)&W1[0*HID + n];
        floatx4 w1 = *(const floatx4*)&W1[1*HID + n];
        floatx4 w2 = *(const floatx4*)&W1[2*HID + n];
        floatx4 bn = *(const floatx4*)&b1[n];
        #pragma unroll
        for (int e = 0; e < 4; ++e) {
          float z  = fmaf(x2, w2[e], fmaf(x1, w1[e], fmaf(x0, w0[e], bn[e])));
          float a  = tanh_fast(z);
          float dd = 1.0f - a*a;
          float wsq = w0[e]*w0[e] + w1[e]*w1[e] + w2[e]*w2[e];
          o[0][jj*4+e] = (_Float16)a;
          o[1][jj*4+e] = (_Float16)(dd*w0[e]);
          o[2][jj*4+e] = (_Float16)(dd*w1[e]);
          o[3][jj*4+e] = (_Float16)(dd*w2[e]);
          o[4][jj*4+e] = (_Float16)(-2.0f*a*dd*wsq);
        }
      }
      #pragma unroll
      for (int s = 0; s < NSTR; ++s)
        *(half8*)(&X[s*PTS + p][c0 + ch*8]) = *(half8*)(o[s]);
    }
  }
  __syncthreads();

  // ---------------- Layers 2,3: 256 -> 256 (MFMA) ----------------
  const int colbase = wave*64 + m*4;   // this lane's 4 consecutive logical cols
  for (int L = 0; L < 2; ++L) {
    const _Float16* Wp = Wpack + (size_t)L * 65536;
    const float* bb = L ? b3 : b2;

    floatx4 acc[NSTR][4];
    #pragma unroll
    for (int s = 0; s < NSTR; ++s)
      #pragma unroll
      for (int c = 0; c < 4; ++c)
        acc[s][c] = (floatx4){0.0f, 0.0f, 0.0f, 0.0f};

    // B-frag base for this wave's 4 tiles (c stride 512 halves, kc stride 8192)
    const _Float16* wb = Wp + (((size_t)(wave*4)*64 + lane) << 3);

    half8 bcur[4], bnxt[4];
    #pragma unroll
    for (int c = 0; c < 4; ++c)
      bcur[c] = *(const half8*)(wb + c*512);

    for (int kc = 0; kc < 8; ++kc) {
      const int kn = (kc + 1) & 7;               // branchless prefetch (last wraps, harmless)
      #pragma unroll
      for (int c = 0; c < 4; ++c)
        bnxt[c] = *(const half8*)(wb + (size_t)kn*8192 + c*512);
      half8 afrag[NSTR];
      #pragma unroll
      for (int s = 0; s < NSTR; ++s)
        afrag[s] = *(const half8*)(&X[s*PTS + m][kc*32 + q*8]);
      #pragma unroll
      for (int s = 0; s < NSTR; ++s)
        #pragma unroll
        for (int c = 0; c < 4; ++c)
          acc[s][c] = __builtin_amdgcn_mfma_f32_16x16x32_f16(afrag[s], bcur[c], acc[s][c], 0, 0, 0);
      #pragma unroll
      for (int c = 0; c < 4; ++c)
        bcur[c] = bnxt[c];
    }
    __syncthreads();   // everyone done reading X -> safe to overwrite in place

    floatx4 bv = *(const floatx4*)&bb[colbase];
    #pragma unroll
    for (int r = 0; r < 4; ++r) {
      const int p = q*4 + r;          // D-layout: row = quad*4 + reg
      _Float16 o[NSTR][4];
      #pragma unroll
      for (int c = 0; c < 4; ++c) {   // c-th tile = logical col colbase+c
        float z  = acc[0][c][r] + bv[c];
        float a  = tanh_fast(z);
        float dd = 1.0f - a*a;
        float zp0 = acc[1][c][r], zp1 = acc[2][c][r], zp2 = acc[3][c][r];
        float zpp = acc[4][c][r];
        float s2  = zp0*zp0 + zp1*zp1 + zp2*zp2;
        o[0][c] = (_Float16)a;
        o[1][c] = (_Float16)(dd*zp0);
        o[2][c] = (_Float16)(dd*zp1);
        o[3][c] = (_Float16)(dd*zp2);
        o[4][c] = (_Float16)(fmaf(dd, zpp, -2.0f*a*dd*s2));
      }
      #pragma unroll
      for (int s = 0; s < NSTR; ++s)
        *(half4v*)(&X[s*PTS + p][colbase]) = *(half4v*)(o[s]);  // 8B, conflict-free
    }
    __syncthreads();
  }

  // ---------------- Layer 4: 256 -> 1, residual, per-block reduction ----------------
  float resacc = 0.0f;
  #pragma unroll
  for (int pp = 0; pp < 4; ++pp) {
    const int p = wave*4 + pp;
    half4v  xu = *(const half4v*)&X[0*PTS + p][lane*4];
    half4v  xt = *(const half4v*)&X[4*PTS + p][lane*4];
    floatx4 w4 = *(const floatx4*)&W4[lane*4];
    float su = 0.0f, st = 0.0f;
    #pragma unroll
    for (int e = 0; e < 4; ++e) {
      su = fmaf((float)xu[e], w4[e], su);
      st = fmaf((float)xt[e], w4[e], st);
    }
    #pragma unroll
    for (int off = 32; off; off >>= 1) {
      su += __shfl_down(su, off);
      st += __shfl_down(st, off);
    }
    if (lane == 0) {
      float u   = su + b4[0];
      float res = st + K2F * u;
      resacc = fmaf(res, res, resacc);
    }
  }
  if (lane == 0) sred[wave] = resacc;
  __syncthreads();
  if (tid == 0)
    part[blockIdx.x] = sred[0] + sred[1] + sred[2] + sred[3];   // plain store, no atomic
}

// 16384 block partials -> single mean; one block, no atomics.
__global__ void reduce_kernel(const float* __restrict__ part, float* __restrict__ out,
                              int nblk, float scale) {
  float s = 0.0f;
  for (int i = threadIdx.x; i < (nblk >> 2); i += 256) {
    floatx4 v = *(const floatx4*)&part[i << 2];
    s += (v[0] + v[1]) + (v[2] + v[3]);
  }
  #pragma unroll
  for (int off = 32; off; off >>= 1) s += __shfl_down(s, off);
  __shared__ float sm[4];
  if ((threadIdx.x & 63) == 0) sm[threadIdx.x >> 6] = s;
  __syncthreads();
  if (threadIdx.x == 0) out[0] = ((sm[0] + sm[1]) + (sm[2] + sm[3])) * scale;
}

extern "C" void kernel_launch(void* const* d_in, const int* in_sizes, int n_in,
                              void* d_out, int out_size, void* d_ws, size_t ws_size,
                              hipStream_t stream) {
  const float* inputs = (const float*)d_in[0];
  const float* W1 = (const float*)d_in[1];
  const float* b1 = (const float*)d_in[2];
  const float* W2 = (const float*)d_in[3];
  const float* b2 = (const float*)d_in[4];
  const float* W3 = (const float*)d_in[5];
  const float* b3 = (const float*)d_in[6];
  const float* W4 = (const float*)d_in[7];
  const float* b4 = (const float*)d_in[8];
  float* out = (float*)d_out;

  _Float16* wp   = (_Float16*)d_ws;                       // 256 KiB packed weights
  float*    part = (float*)((char*)d_ws + 2*65536*2);     // + 64 KiB block partials

  int N    = in_sizes[0] / 3;   // 262144
  int nblk = N / PTS;           // 16384

  pack_kernel<<<64, 256, 0, stream>>>(W2, W3, wp);
  helm_kernel<<<nblk, 256, 0, stream>>>(inputs, W1, b1, b2, b3, W4, b4, wp, part);
  reduce_kernel<<<1, 256, 0, stream>>>(part, out, nblk, 1.0f / (float)N);
}

// Round 5
// 402.384 us; speedup vs baseline: 2.3273x; 1.1623x over previous
//
#include <hip/hip_runtime.h>
#include <math.h>

#define HID 256
#define PTS 16                 // points per block
#define NSTR 5                 // value, g0, g1, g2, laplacian-sum T
#define ROWS (NSTR*PTS)        // 80
#define PITCH 272              // halves; 544B row stride; A-frag reads near bank floor

typedef __fp16  fp16x2 __attribute__((ext_vector_type(2)));
typedef _Float16 half8  __attribute__((ext_vector_type(8)));
typedef float   floatx4 __attribute__((ext_vector_type(4)));

constexpr double PI_D = 3.14159265358979323846;
constexpr float K2F = (float)((343.0/(2.0*PI_D*1000.0))*(343.0/(2.0*PI_D*1000.0)));

union H2U { fp16x2 h; unsigned int u; };
__device__ __forceinline__ unsigned int pk(float a, float b) {
  H2U t; t.h = __builtin_amdgcn_cvt_pkrtz(a, b); return t.u;
}

__device__ __forceinline__ float tanh_fast(float z) {
  // tanh(z) = 1 - 2/(exp2(z*2*log2e)+1); v_exp_f32 is 2^x
  float e = __builtin_amdgcn_exp2f(z * 2.8853900817779268f);
  return 1.0f - 2.0f * __builtin_amdgcn_rcpf(e + 1.0f);
}

// Pack W2,W3 (fp32 row-major [k][n]) into fp16 B-fragment order for
// v_mfma_f32_16x16x32_f16, with a COLUMN PERMUTATION so one lane's 4 tiles
// hold 4 CONSECUTIVE logical columns: tile nt=w*4+c, slot m -> n = w*64+m*4+c
__global__ void pack_kernel(const float* __restrict__ W2, const float* __restrict__ W3,
                            _Float16* __restrict__ out) {
  int t = blockIdx.x * blockDim.x + threadIdx.x;   // 0..16383
  int l    = t >> 13;
  int rem  = t & 8191;
  int kc   = rem >> 10;
  int nt   = (rem >> 6) & 15;
  int lane = rem & 63;
  const float* W = l ? W3 : W2;
  int k0 = kc*32 + ((lane >> 4) << 3);
  int n  = (nt >> 2)*64 + (lane & 15)*4 + (nt & 3);   // permuted column
  _Float16* o = out + (size_t)t * 8;
  #pragma unroll
  for (int j = 0; j < 8; ++j)
    o[j] = (_Float16)W[(size_t)(k0 + j)*HID + n];
}

__global__ __launch_bounds__(256, 3) void helm_kernel(
    const float* __restrict__ inputs,
    const float* __restrict__ W1, const float* __restrict__ b1,
    const float* __restrict__ b2, const float* __restrict__ b3,
    const float* __restrict__ W4, const float* __restrict__ b4,
    const _Float16* __restrict__ Wpack,   // [2][65536] fp16, B-frag packed+permuted
    float* __restrict__ part)             // [gridDim.x] block partial sums
{
  __shared__ __align__(16) _Float16 X[ROWS][PITCH];

  const int tid  = threadIdx.x;
  const int lane = tid & 63;
  const int wave = tid >> 6;
  const int m    = lane & 15;
  const int q    = lane >> 4;

  const int pbase = blockIdx.x * PTS;

  // ---------------- Layer 1: 3 -> 256 (VALU), packed staging ----------------
  {
    const int p  = tid >> 4;          // one point per 16 threads
    const int c0 = (tid & 15) * 16;   // 16 columns per thread
    const float x0 = inputs[(size_t)(pbase + p)*3 + 0];
    const float x1 = inputs[(size_t)(pbase + p)*3 + 1];
    const float x2 = inputs[(size_t)(pbase + p)*3 + 2];
    #pragma unroll
    for (int ch = 0; ch < 2; ++ch) {
      float v[NSTR][8];
      #pragma unroll
      for (int jj = 0; jj < 2; ++jj) {
        const int n = c0 + ch*8 + jj*4;
        floatx4 w0 = *(const floatx4*)&W1[0*HID + n];
        floatx4 w1 = *(const floatx4*)&W1[1*HID + n];
        floatx4 w2 = *(const floatx4*)&W1[2*HID + n];
        floatx4 bn = *(const floatx4*)&b1[n];
        #pragma unroll
        for (int e = 0; e < 4; ++e) {
          float z  = fmaf(x2, w2[e], fmaf(x1, w1[e], fmaf(x0, w0[e], bn[e])));
          float a  = tanh_fast(z);
          float dd = 1.0f - a*a;
          float wsq = fmaf(w0[e], w0[e], fmaf(w1[e], w1[e], w2[e]*w2[e]));
          v[0][jj*4+e] = a;
          v[1][jj*4+e] = dd*w0[e];
          v[2][jj*4+e] = dd*w1[e];
          v[3][jj*4+e] = dd*w2[e];
          v[4][jj*4+e] = -2.0f*a*dd*wsq;
        }
      }
      #pragma unroll
      for (int s = 0; s < NSTR; ++s) {
        uint4 u;
        u.x = pk(v[s][0], v[s][1]); u.y = pk(v[s][2], v[s][3]);
        u.z = pk(v[s][4], v[s][5]); u.w = pk(v[s][6], v[s][7]);
        *(uint4*)&X[s*PTS + p][c0 + ch*8] = u;   // b128, 16B aligned
      }
    }
  }
  __syncthreads();

  const int colbase = wave*64 + m*4;   // this lane's 4 consecutive logical cols

  // ---- shared K-loop: X (5 streams) @ Wpack-layer -> acc[5][4] ----
  auto kloop = [&](const _Float16* __restrict__ Wp, floatx4 (&acc)[NSTR][4]) {
    const _Float16* wb = Wp + (((size_t)(wave*4)*64 + lane) << 3);
    #pragma unroll
    for (int kc = 0; kc < 8; ++kc) {
      half8 bfrag[4];
      #pragma unroll
      for (int c = 0; c < 4; ++c)
        bfrag[c] = *(const half8*)(wb + (size_t)kc*8192 + c*512);
      half8 afrag[NSTR];
      #pragma unroll
      for (int s = 0; s < NSTR; ++s)
        afrag[s] = *(const half8*)(&X[s*PTS + m][kc*32 + q*8]);
      #pragma unroll
      for (int s = 0; s < NSTR; ++s)
        #pragma unroll
        for (int c = 0; c < 4; ++c)
          acc[s][c] = __builtin_amdgcn_mfma_f32_16x16x32_f16(afrag[s], bfrag[c], acc[s][c], 0, 0, 0);
    }
  };

  // ---------------- Layer 2: MFMA + combine (writes X) ----------------
  {
    floatx4 acc[NSTR][4];
    #pragma unroll
    for (int s = 0; s < NSTR; ++s)
      #pragma unroll
      for (int c = 0; c < 4; ++c)
        acc[s][c] = (floatx4){0.0f, 0.0f, 0.0f, 0.0f};
    kloop(Wpack, acc);
    __syncthreads();   // all A-reads done; X writable

    floatx4 bv = *(const floatx4*)&b2[colbase];
    #pragma unroll
    for (int r = 0; r < 4; ++r) {
      const int p = q*4 + r;          // D-layout: row = quad*4 + reg
      float va[4], vg0[4], vg1[4], vg2[4], vT[4];
      #pragma unroll
      for (int c = 0; c < 4; ++c) {
        float z  = acc[0][c][r] + bv[c];
        float a  = tanh_fast(z);
        float dd = 1.0f - a*a;
        float z0 = acc[1][c][r], z1 = acc[2][c][r], z2 = acc[3][c][r];
        float zpp = acc[4][c][r];
        float s2 = fmaf(z0, z0, fmaf(z1, z1, z2*z2));
        va[c]  = a;
        vg0[c] = dd*z0; vg1[c] = dd*z1; vg2[c] = dd*z2;
        vT[c]  = fmaf(dd, zpp, -2.0f*a*dd*s2);
      }
      uint2 u;
      u.x = pk(va[0],va[1]);   u.y = pk(va[2],va[3]);   *(uint2*)&X[0*PTS + p][colbase] = u;
      u.x = pk(vg0[0],vg0[1]); u.y = pk(vg0[2],vg0[3]); *(uint2*)&X[1*PTS + p][colbase] = u;
      u.x = pk(vg1[0],vg1[1]); u.y = pk(vg1[2],vg1[3]); *(uint2*)&X[2*PTS + p][colbase] = u;
      u.x = pk(vg2[0],vg2[1]); u.y = pk(vg2[2],vg2[3]); *(uint2*)&X[3*PTS + p][colbase] = u;
      u.x = pk(vT[0],vT[1]);   u.y = pk(vT[2],vT[3]);   *(uint2*)&X[4*PTS + p][colbase] = u;
    }
    __syncthreads();
  }

  // ------- Layer 3 MFMA + fused (combine ∘ layer-4 ∘ residual) -------
  {
    floatx4 acc[NSTR][4];
    #pragma unroll
    for (int s = 0; s < NSTR; ++s)
      #pragma unroll
      for (int c = 0; c < 4; ++c)
        acc[s][c] = (floatx4){0.0f, 0.0f, 0.0f, 0.0f};
    kloop(Wpack + 65536, acc);
    __syncthreads();   // all A-reads done; X reusable as scratch

    floatx4 bv = *(const floatx4*)&b3[colbase];
    floatx4 w4 = *(const floatx4*)&W4[colbase];
    float su[4] = {0,0,0,0}, st[4] = {0,0,0,0};
    #pragma unroll
    for (int r = 0; r < 4; ++r)
      #pragma unroll
      for (int c = 0; c < 4; ++c) {
        float z  = acc[0][c][r] + bv[c];
        float a  = tanh_fast(z);
        float dd = 1.0f - a*a;
        float z0 = acc[1][c][r], z1 = acc[2][c][r], z2 = acc[3][c][r];
        float zpp = acc[4][c][r];
        float s2 = fmaf(z0, z0, fmaf(z1, z1, z2*z2));
        float T  = fmaf(dd, zpp, -2.0f*a*dd*s2);
        su[r] = fmaf(a, w4[c], su[r]);   // u-partial for point p=q*4+r
        st[r] = fmaf(T, w4[c], st[r]);   // laplacian-partial
      }

    // reduce the 16 m-lanes of each quad (lanes q*16..q*16+15 share points)
    #pragma unroll
    for (int off = 8; off >= 1; off >>= 1)
      #pragma unroll
      for (int r = 0; r < 4; ++r) {
        su[r] += __shfl_down(su[r], off);
        st[r] += __shfl_down(st[r], off);
      }
    float* S = (float*)X;   // scratch: 128 floats, reuse of X (post-barrier)
    if (m == 0) {
      #pragma unroll
      for (int r = 0; r < 4; ++r) {
        S[(q*4 + r)*8 + wave]     = su[r];
        S[(q*4 + r)*8 + 4 + wave] = st[r];
      }
    }
  }
  __syncthreads();

  if (wave == 0) {
    const float* S = (const float*)X;
    int pidx = lane >> 2, w = lane & 3;
    float suc = S[pidx*8 + w];
    float stc = S[pidx*8 + 4 + w];
    suc += __shfl_down(suc, 1); suc += __shfl_down(suc, 2);
    stc += __shfl_down(stc, 1); stc += __shfl_down(stc, 2);
    float sq = 0.0f;
    if ((lane & 3) == 0) {
      float u   = suc + b4[0];
      float res = fmaf(K2F, u, stc);
      sq = res * res;
    }
    sq += __shfl_down(sq, 4); sq += __shfl_down(sq, 8);
    sq += __shfl_down(sq, 16); sq += __shfl_down(sq, 32);
    if (lane == 0) part[blockIdx.x] = sq;
  }
}

// 16384 block partials -> single mean; one block, no atomics.
__global__ void reduce_kernel(const float* __restrict__ part, float* __restrict__ out,
                              int nblk, float scale) {
  float s = 0.0f;
  for (int i = threadIdx.x; i < (nblk >> 2); i += 256) {
    floatx4 v = *(const floatx4*)&part[i << 2];
    s += (v[0] + v[1]) + (v[2] + v[3]);
  }
  #pragma unroll
  for (int off = 32; off; off >>= 1) s += __shfl_down(s, off);
  __shared__ float sm[4];
  if ((threadIdx.x & 63) == 0) sm[threadIdx.x >> 6] = s;
  __syncthreads();
  if (threadIdx.x == 0) out[0] = ((sm[0] + sm[1]) + (sm[2] + sm[3])) * scale;
}

extern "C" void kernel_launch(void* const* d_in, const int* in_sizes, int n_in,
                              void* d_out, int out_size, void* d_ws, size_t ws_size,
                              hipStream_t stream) {
  const float* inputs = (const float*)d_in[0];
  const float* W1 = (const float*)d_in[1];
  const float* b1 = (const float*)d_in[2];
  const float* W2 = (const float*)d_in[3];
  const float* b2 = (const float*)d_in[4];
  const float* W3 = (const float*)d_in[5];
  const float* b3 = (const float*)d_in[6];
  const float* W4 = (const float*)d_in[7];
  const float* b4 = (const float*)d_in[8];
  float* out = (float*)d_out;

  _Float16* wp   = (_Float16*)d_ws;                       // 256 KiB packed weights
  float*    part = (float*)((char*)d_ws + 2*65536*2);     // + 64 KiB block partials

  int N    = in_sizes[0] / 3;   // 262144
  int nblk = N / PTS;           // 16384

  pack_kernel<<<64, 256, 0, stream>>>(W2, W3, wp);
  helm_kernel<<<nblk, 256, 0, stream>>>(inputs, W1, b1, b2, b3, W4, b4, wp, part);
  reduce_kernel<<<1, 256, 0, stream>>>(part, out, nblk, 1.0f / (float)N);
}